// Round 9
// baseline (178.535 us; speedup 1.0000x reference)
//
#include <hip/hip_runtime.h>

#define KVOX 30000
#define TP 35
#define NPTS (KVOX * TP)
#define EPS_BN 1e-5f
#define INVN (1.f / (float)NPTS)
#define NSLOT 16

typedef __attribute__((ext_vector_type(8))) short short8_t;   // 8 x bf16
typedef __attribute__((ext_vector_type(4))) float f32x4;
typedef __attribute__((ext_vector_type(4), aligned(4))) float f32x4u;

#define MFMA_BF16 __builtin_amdgcn_mfma_f32_16x16x32_bf16

// ---- ws layout (float offsets) ----
#define SLOTG_OFF 0                  // 16 x 40 (35 used)
#define SLOT2_OFF 640                // 16 x 128
#define SLOT3_OFF 2688               // 16 x 256
#define PAR_A1 6784
#define PAR_C1 6800
#define PAR_A2 6816
#define PAR_C2 6880
#define PAR_A3 6944
#define PAR_C3 7072
#define STATS_FLOATS 7200            // memset region
#define W2T_OFF 7200                 // [64 u][32 k] bf16 = 1024 f
#define WDT_OFF 8224                 // [128 u][128 k] bf16 (sign-folded) = 8192 f
#define M3_OFF 16416                 // KVOX*128 bf16 = KVOX*64 floats
#define SMALL_FLOATS (16416 + KVOX * 64)
#define H1G_OFF SMALL_FLOATS         // per-4vox-block records
#define REC_DW 1224                  // 1120 h1 + 32 agg1 + 70 mask + 2 pad
#define FULL_FLOATS (H1G_OFF + (KVOX / 4) * REC_DW)

__device__ __forceinline__ ushort f2bf(float f) {
    uint r;
    asm("v_cvt_pk_bf16_f32 %0, %1, %2" : "=v"(r) : "v"(f), "v"(f));
    return (ushort)r;
}
__device__ __forceinline__ uint f2bf2(float lo, float hi) {
    uint r;
    asm("v_cvt_pk_bf16_f32 %0, %1, %2" : "=v"(r) : "v"(lo), "v"(hi));
    return r;
}
__device__ __forceinline__ float bf2f(ushort h) {
    union { uint u; float f; } v; v.u = ((uint)h) << 16; return v.f;
}
__device__ __forceinline__ f32x4 vmax4(f32x4 a, f32x4 b) {
    f32x4 r;
    r[0] = fmaxf(a[0], b[0]); r[1] = fmaxf(a[1], b[1]);
    r[2] = fmaxf(a[2], b[2]); r[3] = fmaxf(a[3], b[3]);
    return r;
}

// ---------------------------------------------------------------------------
// prep (blocks 0..63): W2T; WDT with sign(gd) folded. stats1 (64..319): Gram.
// ---------------------------------------------------------------------------
__global__ __launch_bounds__(256) void k_prep_stats1(
    const float* __restrict__ x,
    const float* __restrict__ W2, const float* __restrict__ Wd,
    const float* __restrict__ gd,
    ushort* __restrict__ w2t, ushort* __restrict__ wdt,
    float* __restrict__ slotG) {
    if (blockIdx.x < 64) {
        int t = blockIdx.x * 256 + threadIdx.x;     // 0..16383
        if (t < 2048) {
            int u = t >> 5, k = t & 31;
            w2t[t] = f2bf(W2[k * 64 + u]);
        }
        int u = t >> 7, k = t & 127;
        float sg = (gd[u] < 0.f) ? -1.f : 1.f;
        wdt[t] = f2bf(Wd[k * 128 + u] * sg);
        return;
    }
    int bid = blockIdx.x - 64;                      // 0..255
    int tid = threadIdx.x;
    int gid = bid * 256 + tid;
    float sx[7], G[28];
#pragma unroll
    for (int c = 0; c < 7; ++c) sx[c] = 0.f;
#pragma unroll
    for (int i = 0; i < 28; ++i) G[i] = 0.f;
    for (size_t p4 = (size_t)gid * 4; p4 < NPTS; p4 += (size_t)65536 * 4) {
        const f32x4u* xp = (const f32x4u*)(x + p4 * 7);
        f32x4 q[7];
#pragma unroll
        for (int c = 0; c < 7; ++c) q[c] = xp[c];
#pragma unroll
        for (int j = 0; j < 4; ++j) {
            float xv[7];
#pragma unroll
            for (int c = 0; c < 7; ++c) {
                int idx = j * 7 + c;
                xv[c] = q[idx >> 2][idx & 3];
                sx[c] += xv[c];
            }
            int idx = 0;
#pragma unroll
            for (int i = 0; i < 7; ++i)
#pragma unroll
                for (int jj = i; jj < 7; ++jj) { G[idx] = fmaf(xv[i], xv[jj], G[idx]); ++idx; }
        }
    }
    int lane = tid & 63;
    int wv = tid >> 6;
    int slot = (bid * 4 + wv) & (NSLOT - 1);
#pragma unroll
    for (int k = 0; k < 35; ++k) {
        float v = (k < 28) ? G[k] : sx[k - 28];
#pragma unroll
        for (int m = 32; m > 0; m >>= 1) v += __shfl_xor(v, m, 64);
        if (lane == 0) atomicAdd(&slotG[slot * 40 + k], v);
    }
}

// ---------------------------------------------------------------------------
// S2: inline BN1 affine + phase A (vectorized x loads) + dump + BN2 stats.
// ---------------------------------------------------------------------------
template <bool DUMP>
__global__ __launch_bounds__(512, 8) void k_stats2(
    const float* __restrict__ x,
    const float* __restrict__ W1, const float* __restrict__ b1,
    const float* __restrict__ g1, const float* __restrict__ be1,
    const ushort* __restrict__ w2t,
    const float* __restrict__ slotG,
    float* __restrict__ slot2, uint* __restrict__ recs) {
    __shared__ __align__(16) ushort h1[144 * 24];
    __shared__ float lmask[144];
    __shared__ float aggp[7 * 64];
    __shared__ __align__(16) ushort agg1bf[64];
    __shared__ __align__(16) uint zeros16[4];
    __shared__ float red[36], parA1[16], parC1[16];
    int tid = threadIdx.x;
    int k0 = blockIdx.x * 4;
    if (tid < 4) zeros16[tid] = 0;
    // ---- inline BN1 affine: reduce slotG, compute parA1/parC1 ----
    if (tid < 35) {
        float s = 0.f;
#pragma unroll
        for (int sl = 0; sl < NSLOT; ++sl) s += slotG[sl * 40 + tid];
        red[tid] = s;
    }
    __syncthreads();
    if (tid < 16) {
        float wv[7];
#pragma unroll
        for (int c = 0; c < 7; ++c) wv[c] = W1[c * 16 + tid];
        float bq = b1[tid];
        float sw = 0.f;
#pragma unroll
        for (int c = 0; c < 7; ++c) sw = fmaf(red[28 + c], wv[c], sw);
        float gq = 0.f;
        int idx = 0;
#pragma unroll
        for (int ii = 0; ii < 7; ++ii)
#pragma unroll
            for (int jj = ii; jj < 7; ++jj) {
                float coef = wv[ii] * wv[jj];
                if (ii != jj) coef *= 2.f;
                gq = fmaf(coef, red[idx], gq);
                ++idx;
            }
        float mr = sw * INVN;
        float mean = mr + bq;
        float ex2 = gq * INVN + 2.f * bq * mr + bq * bq;
        float var = ex2 - mean * mean;
        float av = g1[tid] * rsqrtf(var + EPS_BN);
        parA1[tid] = av;
        parC1[tid] = be1[tid] - mean * av;
    }
    __syncthreads();
    // ---- phase A (vectorized loads) ----
    {
        int u = tid & 15;
        int g = tid >> 4;      // 0..31
        int v = g & 3;
        int th = g >> 2;       // 0..7
        float pmax = 0.f;
        if (th < 7) {
            float b1u = b1[u];
            float a1u = parA1[u], c1u = parC1[u];
            float w1c[7];
#pragma unroll
            for (int c = 0; c < 7; ++c) w1c[c] = W1[c * 16 + u];
            const float* pbase = x + (size_t)(k0 + v) * 245 + th * 35;
#pragma unroll
            for (int i = 0; i < 5; ++i) {
                int t = th * 5 + i;
                f32x4 q0 = *(const f32x4u*)(pbase + i * 7);       // floats 0..3
                f32x4 q1 = *(const f32x4u*)(pbase + i * 7 + 3);   // floats 3..6
                float xv[7] = {q0[0], q0[1], q0[2], q0[3], q1[1], q1[2], q1[3]};
                float sum7 = 0.f;
#pragma unroll
                for (int c = 0; c < 7; ++c) sum7 += xv[c];
                float mkv = (sum7 != 0.f) ? 1.f : 0.f;
                int row = 4 * t + v;
                if (u == 0) lmask[row] = mkv;
                float val = b1u;
#pragma unroll
                for (int c = 0; c < 7; ++c) val = fmaf(xv[c], w1c[c], val);
                val = fmaxf(fmaf(a1u, val, c1u), 0.f);
                pmax = fmaxf(pmax, val);                 // unmasked (ref semantics)
                h1[row * 24 + u] = f2bf(val * mkv);
            }
        } else {
            int row = 140 + v;                            // pad rows
            h1[row * 24 + u] = 0;
            if (u == 0) lmask[row] = 0.f;
        }
        int w = tid >> 6;
        int lane = tid & 63;                              // lane = v*16+u
        if (w < 7) aggp[w * 64 + lane] = pmax;
    }
    __syncthreads();
    if (tid < 64) {
        float m = aggp[tid];
#pragma unroll
        for (int ww = 1; ww < 7; ++ww) m = fmaxf(m, aggp[ww * 64 + tid]);
        agg1bf[tid] = f2bf(m);                            // layout [v*16+u]
    }
    __syncthreads();
    if (DUMP) {
        uint* rec = recs + (size_t)blockIdx.x * REC_DW;
        const uint* h1dw = (const uint*)h1;
        for (int i = tid; i < 1120; i += 512) rec[i] = h1dw[(i >> 3) * 12 + (i & 7)];
        if (tid < 32) rec[1120 + tid] = ((const uint*)agg1bf)[tid];
        if (tid < 70) rec[1152 + tid] = f2bf2(lmask[2 * tid], lmask[2 * tid + 1]);
    }
    // ---- BN2 stats via rank-1 MFMA ----
    int w = tid >> 6, lane = tid & 63, lq = lane >> 4, lr = lane & 15;
    int mh = w >> 2, uq = w & 3;
    int u = uq * 16 + lr;
    short8_t bB = *(const short8_t*)(w2t + u * 32 + (lq & 1) * 8);
    short8_t bP = *(const short8_t*)(w2t + u * 32 + 16 + (lq & 1) * 8);
    const ushort* pap = (lq < 2) ? (agg1bf + (lr & 3) * 16 + (lq & 1) * 8) : (const ushort*)zeros16;
    short8_t pAf = *(const short8_t*)pap;
    f32x4 aP = {0.f, 0.f, 0.f, 0.f};
    aP = MFMA_BF16(pAf, bP, aP, 0, 0, 0);
    f32x4 p1;
    p1[0] = __shfl(aP[0], lr, 64); p1[1] = __shfl(aP[1], lr, 64);
    p1[2] = __shfl(aP[2], lr, 64); p1[3] = __shfl(aP[3], lr, 64);
    f32x4 s1p = {0.f, 0.f, 0.f, 0.f}, s2p = {0.f, 0.f, 0.f, 0.f};
    int mt0 = mh ? 5 : 0, mt1 = mh ? 9 : 5;
    for (int mt = mt0; mt < mt1; ++mt) {
        const ushort* ha = (lq < 2) ? (h1 + (mt * 16 + lr) * 24 + (lq & 1) * 8) : (const ushort*)zeros16;
        short8_t af = *(const short8_t*)ha;
        f32x4 acc = {0.f, 0.f, 0.f, 0.f};
        acc = MFMA_BF16(af, bB, acc, 0, 0, 0);
        f32x4 mk = *(const f32x4*)(lmask + mt * 16 + lq * 4);
        f32x4 am = (acc + p1) * mk;
        s1p += am;
        s2p += am * am;
    }
    float s1 = s1p[0] + s1p[1] + s1p[2] + s1p[3];
    float s2 = s2p[0] + s2p[1] + s2p[2] + s2p[3];
    s1 += __shfl_xor(s1, 16, 64); s1 += __shfl_xor(s1, 32, 64);
    s2 += __shfl_xor(s2, 16, 64); s2 += __shfl_xor(s2, 32, 64);
    if (lq == 0) {
        int slot = blockIdx.x & (NSLOT - 1);
        atomicAdd(&slot2[slot * 128 + u], s1);
        atomicAdd(&slot2[slot * 128 + 64 + u], s2);
    }
}

// ---------------------------------------------------------------------------
// S3 REUSE: inline BN2 affine + stage record + phase B + phase C.
// ---------------------------------------------------------------------------
__global__ __launch_bounds__(512, 8) void k_stage3_reuse(
    const uint* __restrict__ recs,
    const float* __restrict__ b2, const float* __restrict__ g2,
    const float* __restrict__ be2,
    const ushort* __restrict__ w2t, const ushort* __restrict__ wdt,
    const float* __restrict__ bd, const float* __restrict__ gd,
    const float* __restrict__ slot2,
    float* __restrict__ slot3, ushort* __restrict__ m3) {
    __shared__ __align__(16) ushort h1[144 * 24];
    __shared__ __align__(16) ushort h2[144 * 72];
    __shared__ float lmask[144];
    __shared__ __align__(16) uint aggfU[4 * 68];     // [vox][68] f32-bits (max)
    __shared__ __align__(16) ushort agg1bf[64];
    __shared__ __align__(16) uint zeros16[4];
    __shared__ float parA2L[64], parC2L[64];
    int tid = threadIdx.x;
    int k0 = blockIdx.x * 4;
    int w = tid >> 6, lane = tid & 63, lq = lane >> 4, lr = lane & 15;

    // ---- staging + inline BN2 affine ----
    {
        const uint* rec = recs + (size_t)blockIdx.x * REC_DW;
        uint* h1dw = (uint*)h1;
        {
            int i = tid;              h1dw[(i >> 3) * 12 + (i & 7)] = rec[i];
            i = tid + 512;            h1dw[(i >> 3) * 12 + (i & 7)] = rec[i];
            i = tid + 1024; if (i < 1120) h1dw[(i >> 3) * 12 + (i & 7)] = rec[i];
        }
        if (tid < 48) h1dw[140 * 12 + tid] = 0u;     // pad rows 140..143
        if (tid < 32) ((uint*)agg1bf)[tid] = rec[1120 + tid];
        if (tid < 72) {
            if (tid < 70) {
                uint mw = rec[1152 + tid];
                lmask[2 * tid] = bf2f((ushort)(mw & 0xffffu));
                lmask[2 * tid + 1] = bf2f((ushort)(mw >> 16));
            } else {
                int j = 140 + (tid - 70) * 2;
                lmask[j] = 0.f; lmask[j + 1] = 0.f;
            }
        }
        if (tid < 272) aggfU[tid] = 0u;
        if (tid < 4) zeros16[tid] = 0u;
        if (tid < 64) {
            float s = 0.f, q = 0.f;
#pragma unroll
            for (int sl = 0; sl < NSLOT; ++sl) {
                s += slot2[sl * 128 + tid];
                q += slot2[sl * 128 + 64 + tid];
            }
            float bq = b2[tid];
            float mr = s * INVN;
            float mean = mr + bq;
            float ex2 = q * INVN + 2.f * bq * mr + bq * bq;
            float var = ex2 - mean * mean;
            float av = g2[tid] * rsqrtf(var + EPS_BN);
            parA2L[tid] = av;
            parC2L[tid] = fmaf(av, bq, be2[tid] - mean * av);
        }
    }
    __syncthreads();

    // ---- phase B ----
    {
        int mh = w >> 2, uq = w & 3;
        int u = uq * 16 + lr;
        short8_t bB = *(const short8_t*)(w2t + u * 32 + (lq & 1) * 8);
        short8_t bP = *(const short8_t*)(w2t + u * 32 + 16 + (lq & 1) * 8);
        const ushort* pap = (lq < 2) ? (agg1bf + (lr & 3) * 16 + (lq & 1) * 8) : (const ushort*)zeros16;
        short8_t pAf = *(const short8_t*)pap;
        f32x4 aP = {0.f, 0.f, 0.f, 0.f};
        aP = MFMA_BF16(pAf, bP, aP, 0, 0, 0);
        f32x4 p1;
        p1[0] = __shfl(aP[0], lr, 64); p1[1] = __shfl(aP[1], lr, 64);
        p1[2] = __shfl(aP[2], lr, 64); p1[3] = __shfl(aP[3], lr, 64);
        float a2u = parA2L[u];
        float c2u = parC2L[u];
        f32x4 a2p4 = {a2u, a2u, a2u, a2u};
        f32x4 c2p4 = {c2u, c2u, c2u, c2u};
        f32x4 zero4 = {0.f, 0.f, 0.f, 0.f};
        f32x4 av = {0.f, 0.f, 0.f, 0.f};
        int mt0 = mh ? 5 : 0, mt1 = mh ? 9 : 5;
        for (int mt = mt0; mt < mt1; ++mt) {
            const ushort* ha = (lq < 2) ? (h1 + (mt * 16 + lr) * 24 + (lq & 1) * 8) : (const ushort*)zeros16;
            short8_t af = *(const short8_t*)ha;
            f32x4 acc = {0.f, 0.f, 0.f, 0.f};
            acc = MFMA_BF16(af, bB, acc, 0, 0, 0);
            f32x4 mk = *(const f32x4*)(lmask + mt * 16 + lq * 4);
            int m0 = mt * 16 + lq * 4;
            f32x4 am = (acc + p1) * mk;
            f32x4 val = vmax4(a2p4 * am + c2p4, zero4);
            h2[(m0 + 0) * 72 + u] = f2bf(val[0]);
            h2[(m0 + 1) * 72 + u] = f2bf(val[1]);
            h2[(m0 + 2) * 72 + u] = f2bf(val[2]);
            h2[(m0 + 3) * 72 + u] = f2bf(val[3]);
            if (!(mt == 8 && lq == 3)) av = vmax4(av, val);   // exclude pad rows
        }
#pragma unroll
        for (int r = 0; r < 4; ++r) {
            av[r] = fmaxf(av[r], __shfl_xor(av[r], 16, 64));
            av[r] = fmaxf(av[r], __shfl_xor(av[r], 32, 64));
        }
        if (lq == 0) {
#pragma unroll
            for (int r = 0; r < 4; ++r)
                atomicMax(&aggfU[r * 68 + u], __float_as_uint(av[r]));
        }
    }
    __syncthreads();

    // ---- phase C: pw3 = h2@Wd[0:64] + mask*proj2(agg2) ----
    {
        int u = w * 16 + lr;
        short8_t bM0 = *(const short8_t*)(wdt + u * 128 + lq * 8);
        short8_t bM1 = *(const short8_t*)(wdt + u * 128 + 32 + lq * 8);
        short8_t bP0 = *(const short8_t*)(wdt + u * 128 + 64 + lq * 8);
        short8_t bP1 = *(const short8_t*)(wdt + u * 128 + 96 + lq * 8);
        const float* aggf = (const float*)aggfU;
        f32x4 q0 = *(const f32x4*)(aggf + (lr & 3) * 68 + lq * 8);
        f32x4 q1 = *(const f32x4*)(aggf + (lr & 3) * 68 + lq * 8 + 4);
        f32x4 q2 = *(const f32x4*)(aggf + (lr & 3) * 68 + 32 + lq * 8);
        f32x4 q3 = *(const f32x4*)(aggf + (lr & 3) * 68 + 32 + lq * 8 + 4);
        union { uint uu[4]; short8_t s8; } pc0, pc1;
        pc0.uu[0] = f2bf2(q0[0], q0[1]); pc0.uu[1] = f2bf2(q0[2], q0[3]);
        pc0.uu[2] = f2bf2(q1[0], q1[1]); pc0.uu[3] = f2bf2(q1[2], q1[3]);
        pc1.uu[0] = f2bf2(q2[0], q2[1]); pc1.uu[1] = f2bf2(q2[2], q2[3]);
        pc1.uu[2] = f2bf2(q3[0], q3[1]); pc1.uu[3] = f2bf2(q3[2], q3[3]);
        f32x4 aP = {0.f, 0.f, 0.f, 0.f};
        aP = MFMA_BF16(pc0.s8, bP0, aP, 0, 0, 0);
        aP = MFMA_BF16(pc1.s8, bP1, aP, 0, 0, 0);
        f32x4 p2;
        p2[0] = __shfl(aP[0], lr, 64); p2[1] = __shfl(aP[1], lr, 64);
        p2[2] = __shfl(aP[2], lr, 64); p2[3] = __shfl(aP[3], lr, 64);
        f32x4 s1p = {0.f, 0.f, 0.f, 0.f}, s2p = {0.f, 0.f, 0.f, 0.f};
        f32x4 mx = {-1e30f, -1e30f, -1e30f, -1e30f};
#pragma unroll
        for (int mt = 0; mt < 9; ++mt) {
            const ushort* hrow = h2 + (mt * 16 + lr) * 72;
            short8_t a0 = *(const short8_t*)(hrow + lq * 8);
            short8_t a1 = *(const short8_t*)(hrow + 32 + lq * 8);
            f32x4 acc = {0.f, 0.f, 0.f, 0.f};
            acc = MFMA_BF16(a0, bM0, acc, 0, 0, 0);
            acc = MFMA_BF16(a1, bM1, acc, 0, 0, 0);
            f32x4 mk = *(const f32x4*)(lmask + mt * 16 + lq * 4);
            f32x4 am = (acc + p2) * mk;
            s1p += am;
            s2p += am * am;
            if (mt < 8 || lq < 3) mx = vmax4(mx, am);        // rows 140..143 excluded
        }
#pragma unroll
        for (int r = 0; r < 4; ++r) {
            mx[r] = fmaxf(mx[r], __shfl_xor(mx[r], 16, 64));
            mx[r] = fmaxf(mx[r], __shfl_xor(mx[r], 32, 64));
        }
        float s1 = s1p[0] + s1p[1] + s1p[2] + s1p[3];
        float s2 = s2p[0] + s2p[1] + s2p[2] + s2p[3];
        s1 += __shfl_xor(s1, 16, 64); s1 += __shfl_xor(s1, 32, 64);
        s2 += __shfl_xor(s2, 16, 64); s2 += __shfl_xor(s2, 32, 64);
        if (lq == 0) {
            float sg = (gd[u] < 0.f) ? -1.f : 1.f;
            float bdu = bd[u];
#pragma unroll
            for (int r = 0; r < 4; ++r)
                m3[(size_t)(k0 + r) * 128 + u] = f2bf(fmaf(sg, mx[r], bdu));
            int slot = blockIdx.x & (NSLOT - 1);
            atomicAdd(&slot3[slot * 256 + u], s1);
            atomicAdd(&slot3[slot * 256 + 128 + u], s2);
        }
    }
}

// ---------------------------------------------------------------------------
// Finalize: inline BN3 affine (sign-aware, bias-folded) + transpose.
// ---------------------------------------------------------------------------
__global__ __launch_bounds__(256) void k_final_ws(const ushort* __restrict__ m3,
                                                  const float* __restrict__ slot3,
                                                  const float* __restrict__ gd,
                                                  const float* __restrict__ bed,
                                                  const float* __restrict__ bd,
                                                  float* __restrict__ out) {
    __shared__ float tile[32][33];
    __shared__ float a3L[32], c3L[32];
    int tid = threadIdx.x;
    int tx = tid & 31;
    int ty = tid >> 5;
    int v0 = blockIdx.x * 32;
    int u0 = blockIdx.y * 32;
    if (tid < 32) {
        int u = u0 + tid;
        float s = 0.f, q = 0.f;
#pragma unroll
        for (int sl = 0; sl < NSLOT; ++sl) {
            s += slot3[sl * 256 + u];
            q += slot3[sl * 256 + 128 + u];
        }
        float sg = (gd[u] < 0.f) ? -1.f : 1.f;
        s *= sg;
        float b = bd[u];
        float mr = s * INVN;
        float mean = mr + b;
        float ex2 = q * INVN + 2.f * b * mr + b * b;
        float var = ex2 - mean * mean;
        float av = gd[u] * rsqrtf(var + EPS_BN);
        a3L[tid] = av;
        c3L[tid] = bed[u] - mean * av;
    }
    __syncthreads();
#pragma unroll
    for (int r = ty; r < 32; r += 8) {
        int v = v0 + r;
        float y = 0.f;
        if (v < KVOX) {
            float a = a3L[tx], c = c3L[tx];
            float val = bf2f(m3[(size_t)v * 128 + u0 + tx]);
            y = a * val + c;
            y = (y >= 0.f) ? y : 0.1f * y;
        }
        tile[r][tx] = y;
    }
    __syncthreads();
#pragma unroll
    for (int r = ty; r < 32; r += 8) {
        int u = u0 + r, v = v0 + tx;
        if (v < KVOX) out[(size_t)u * KVOX + v] = tile[tx][r];
    }
}

// ===========================================================================
// Fallback path kernels (ws too small for recs) — 16-slot variants
// ===========================================================================
__global__ void k_affine1g(const float* __restrict__ slotG,
                           const float* __restrict__ W1, const float* __restrict__ b1,
                           const float* __restrict__ g1, const float* __restrict__ be1,
                           float* __restrict__ pa, float* __restrict__ pc) {
    __shared__ float red[35];
    int t = threadIdx.x;
    if (t < 35) {
        float s = 0.f;
#pragma unroll
        for (int sl = 0; sl < NSLOT; ++sl) s += slotG[sl * 40 + t];
        red[t] = s;
    }
    __syncthreads();
    if (t < 16) {
        float wv[7];
#pragma unroll
        for (int c = 0; c < 7; ++c) wv[c] = W1[c * 16 + t];
        float b = b1[t];
        float sw = 0.f;
#pragma unroll
        for (int c = 0; c < 7; ++c) sw = fmaf(red[28 + c], wv[c], sw);
        float gq = 0.f;
        int idx = 0;
#pragma unroll
        for (int i = 0; i < 7; ++i)
#pragma unroll
            for (int j = i; j < 7; ++j) {
                float coef = wv[i] * wv[j];
                if (i != j) coef *= 2.f;
                gq = fmaf(coef, red[idx], gq);
                ++idx;
            }
        float mr = sw * INVN;
        float mean = mr + b;
        float ex2 = gq * INVN + 2.f * b * mr + b * b;
        float var = ex2 - mean * mean;
        float av = g1[t] * rsqrtf(var + EPS_BN);
        pa[t] = av;
        pc[t] = be1[t] - mean * av;
    }
}

__global__ void k_affine_b(const float* __restrict__ slots,
                           const float* __restrict__ g,
                           const float* __restrict__ be,
                           const float* __restrict__ bias,
                           float* __restrict__ pa, float* __restrict__ pc,
                           int C) {
    int u = threadIdx.x;
    if (u >= C) return;
    float s = 0.f, q = 0.f;
    for (int sl = 0; sl < NSLOT; ++sl) {
        s += slots[sl * 2 * C + u];
        q += slots[sl * 2 * C + C + u];
    }
    float b = bias[u];
    float mr = s * INVN;
    float mean = mr + b;
    float ex2 = q * INVN + 2.f * b * mr + b * b;
    float var = ex2 - mean * mean;
    float av = g[u] * rsqrtf(var + EPS_BN);
    pa[u] = av;
    pc[u] = be[u] - mean * av;
}

__global__ void k_affine_b3(const float* __restrict__ slots,
                            const float* __restrict__ g,
                            const float* __restrict__ be,
                            const float* __restrict__ bias,
                            float* __restrict__ pa, float* __restrict__ pc,
                            int C) {
    int u = threadIdx.x;
    if (u >= C) return;
    float s = 0.f, q = 0.f;
    for (int sl = 0; sl < NSLOT; ++sl) {
        s += slots[sl * 2 * C + u];
        q += slots[sl * 2 * C + C + u];
    }
    float sg = (g[u] < 0.f) ? -1.f : 1.f;
    s *= sg;
    float b = bias[u];
    float mr = s * INVN;
    float mean = mr + b;
    float ex2 = q * INVN + 2.f * b * mr + b * b;
    float var = ex2 - mean * mean;
    float av = g[u] * rsqrtf(var + EPS_BN);
    pa[u] = av;
    pc[u] = be[u] - mean * av;
}

__device__ __forceinline__ void phaseA_leg(
    int k0, int tid,
    const float* __restrict__ x,
    const float* __restrict__ W1, const float* __restrict__ b1,
    const float* __restrict__ a1, const float* __restrict__ c1,
    ushort* __restrict__ h1, float* __restrict__ lmask, float* __restrict__ aggp) {
    int u = tid & 15;
    int g = tid >> 4;
    int v = g & 1;
    int th = g >> 1;
    float pmax = 0.f;
    if (th < 7) {
        float b1u = b1[u];
        float a1u = a1[u], c1u = c1[u];
        float w1c[7];
#pragma unroll
        for (int c = 0; c < 7; ++c) w1c[c] = W1[c * 16 + u];
#pragma unroll
        for (int i = 0; i < 5; ++i) {
            int t = th * 5 + i;
            const float* xp = x + ((size_t)(k0 + v) * TP + t) * 7;
            float xv[7];
            float sum7 = 0.f;
#pragma unroll
            for (int c = 0; c < 7; ++c) { xv[c] = xp[c]; sum7 += xv[c]; }
            float mkv = (sum7 != 0.f) ? 1.f : 0.f;
            if (u == 0) lmask[v * TP + t] = mkv;
            float val = b1u;
#pragma unroll
            for (int c = 0; c < 7; ++c) val = fmaf(xv[c], w1c[c], val);
            val = fmaxf(fmaf(a1u, val, c1u), 0.f);
            pmax = fmaxf(pmax, val);
            h1[(v * TP + t) * 40 + u] = f2bf(val * mkv);
        }
    } else {
#pragma unroll
        for (int i = 0; i < 5; ++i) {
            int row = 70 + (g & 1) * 5 + i;
            h1[row * 40 + u] = 0;
            if (u == 0) lmask[row] = 0.f;
        }
    }
    pmax = fmaxf(pmax, __shfl_xor(pmax, 32, 64));
    int w = tid >> 6;
    int lane = tid & 63;
    if (lane < 32) aggp[w * 32 + lane] = pmax;
    __syncthreads();
    {
        int uu = tid & 15;
        int r0 = tid >> 4;
        float g0 = fmaxf(fmaxf(aggp[uu], aggp[32 + uu]),
                         fmaxf(aggp[64 + uu], aggp[96 + uu]));
        float g1v = fmaxf(fmaxf(aggp[16 + uu], aggp[48 + uu]),
                          fmaxf(aggp[80 + uu], aggp[112 + uu]));
        ushort a0 = f2bf(g0), a1b = f2bf(g1v);
#pragma unroll
        for (int j = 0; j < 5; ++j) {
            int row = r0 + j * 16;
            float mkv = lmask[row];
            h1[row * 40 + 16 + uu] = (mkv != 0.f) ? ((row < TP) ? a0 : a1b) : (ushort)0;
        }
    }
    __syncthreads();
}

__global__ __launch_bounds__(256) void k_stats2_fb(
    const float* __restrict__ x,
    const float* __restrict__ W1, const float* __restrict__ b1,
    const ushort* __restrict__ w2t,
    const float* __restrict__ ws,
    float* __restrict__ slot2) {
    __shared__ __align__(16) ushort h1[80 * 40];
    __shared__ float lmask[80];
    __shared__ float aggp[128];
    int tid = threadIdx.x;
    int k0 = blockIdx.x * 2;
    phaseA_leg(k0, tid, x, W1, b1, ws + PAR_A1, ws + PAR_C1, h1, lmask, aggp);
    int w = tid >> 6, lane = tid & 63, lq = lane >> 4, lr = lane & 15;
    int u = w * 16 + lr;
    short8_t bfrag = *(const short8_t*)(w2t + u * 32 + lq * 8);
    float s1v = 0.f, s2v = 0.f;
#pragma unroll
    for (int mt = 0; mt < 5; ++mt) {
        short8_t afrag = *(const short8_t*)(h1 + (mt * 16 + lr) * 40 + lq * 8);
        f32x4 acc = {0.f, 0.f, 0.f, 0.f};
        acc = MFMA_BF16(afrag, bfrag, acc, 0, 0, 0);
#pragma unroll
        for (int r = 0; r < 4; ++r) { s1v += acc[r]; s2v = fmaf(acc[r], acc[r], s2v); }
    }
    s1v += __shfl_xor(s1v, 16, 64); s1v += __shfl_xor(s1v, 32, 64);
    s2v += __shfl_xor(s2v, 16, 64); s2v += __shfl_xor(s2v, 32, 64);
    if (lq == 0) {
        int slot = blockIdx.x & (NSLOT - 1);
        atomicAdd(&slot2[slot * 128 + u], s1v);
        atomicAdd(&slot2[slot * 128 + 64 + u], s2v);
    }
}

__global__ __launch_bounds__(256) void k_stage3_fb(
    const float* __restrict__ x,
    const float* __restrict__ W1, const float* __restrict__ b1,
    const float* __restrict__ b2,
    const ushort* __restrict__ w2t, const ushort* __restrict__ wdt,
    const float* __restrict__ bd, const float* __restrict__ gd,
    const float* __restrict__ ws,
    float* __restrict__ slot3, float* __restrict__ outbuf) {
    __shared__ __align__(16) ushort h1[80 * 40];
    __shared__ __align__(16) ushort h2[80 * 136];
    __shared__ float lmask[80];
    __shared__ float aggp[128];
    __shared__ ushort agg2bf[128];
    int tid = threadIdx.x;
    int k0 = blockIdx.x * 2;
    int w = tid >> 6, lane = tid & 63, lq = lane >> 4, lr = lane & 15;
    phaseA_leg(k0, tid, x, W1, b1, ws + PAR_A1, ws + PAR_C1, h1, lmask, aggp);
    int u0 = w * 32;
    short8_t bfr[2][4];
#pragma unroll
    for (int s = 0; s < 2; ++s)
#pragma unroll
        for (int kk = 0; kk < 4; ++kk)
            bfr[s][kk] = *(const short8_t*)(wdt + ((u0 + s * 16 + lr) * 128 + kk * 32 + lq * 8));
    {
        int u = w * 16 + lr;
        short8_t bfrag = *(const short8_t*)(w2t + u * 32 + lq * 8);
        float a2u = ws[PAR_A2 + u];
        float c2p = fmaf(a2u, b2[u], ws[PAR_C2 + u]);
        float aggv0 = 0.f, aggv1 = 0.f;
#pragma unroll
        for (int mt = 0; mt < 5; ++mt) {
            short8_t afrag = *(const short8_t*)(h1 + (mt * 16 + lr) * 40 + lq * 8);
            f32x4 acc = {0.f, 0.f, 0.f, 0.f};
            acc = MFMA_BF16(afrag, bfrag, acc, 0, 0, 0);
#pragma unroll
            for (int r = 0; r < 4; ++r) {
                int m = mt * 16 + lq * 4 + r;
                float val = fmaxf(fmaf(a2u, acc[r], c2p), 0.f);
                float vm = (m < 70) ? val : 0.f;
                if (m < TP) aggv0 = fmaxf(aggv0, vm); else aggv1 = fmaxf(aggv1, vm);
                h2[m * 136 + u] = f2bf(val * lmask[m]);
            }
        }
        aggv0 = fmaxf(aggv0, __shfl_xor(aggv0, 16, 64));
        aggv0 = fmaxf(aggv0, __shfl_xor(aggv0, 32, 64));
        aggv1 = fmaxf(aggv1, __shfl_xor(aggv1, 16, 64));
        aggv1 = fmaxf(aggv1, __shfl_xor(aggv1, 32, 64));
        if (lq == 0) { agg2bf[u] = f2bf(aggv0); agg2bf[64 + u] = f2bf(aggv1); }
    }
    __syncthreads();
    {
        int c = tid & 63;
        int r0 = tid >> 6;
        ushort a0 = agg2bf[c], a1v = agg2bf[64 + c];
#pragma unroll
        for (int j = 0; j < 20; ++j) {
            int row = r0 + j * 4;
            float mkv = lmask[row];
            h2[row * 136 + 64 + c] = (mkv != 0.f) ? ((row < TP) ? a0 : a1v) : (ushort)0;
        }
    }
    __syncthreads();
    {
        float mxa[2][2], s1a[2], s2a[2];
#pragma unroll
        for (int s = 0; s < 2; ++s) {
            s1a[s] = 0.f; s2a[s] = 0.f;
            mxa[s][0] = -1e30f; mxa[s][1] = -1e30f;
        }
#pragma unroll
        for (int mt = 0; mt < 5; ++mt) {
            short8_t af[4];
#pragma unroll
            for (int kk = 0; kk < 4; ++kk)
                af[kk] = *(const short8_t*)(h2 + (mt * 16 + lr) * 136 + kk * 32 + lq * 8);
#pragma unroll
            for (int s = 0; s < 2; ++s) {
                f32x4 acc = {0.f, 0.f, 0.f, 0.f};
#pragma unroll
                for (int kk = 0; kk < 4; ++kk)
                    acc = MFMA_BF16(af[kk], bfr[s][kk], acc, 0, 0, 0);
#pragma unroll
                for (int r = 0; r < 4; ++r) {
                    float a = acc[r];
                    s1a[s] += a;
                    s2a[s] = fmaf(a, a, s2a[s]);
                    int m = mt * 16 + lq * 4 + r;
                    if (mt <= 1) mxa[s][0] = fmaxf(mxa[s][0], a);
                    else if (mt == 3) mxa[s][1] = fmaxf(mxa[s][1], a);
                    else if (mt == 2) { if (m < TP) mxa[s][0] = fmaxf(mxa[s][0], a); else mxa[s][1] = fmaxf(mxa[s][1], a); }
                    else { if (m < 70) mxa[s][1] = fmaxf(mxa[s][1], a); }
                }
            }
        }
#pragma unroll
        for (int s = 0; s < 2; ++s) {
#pragma unroll
            for (int v = 0; v < 2; ++v) {
                mxa[s][v] = fmaxf(mxa[s][v], __shfl_xor(mxa[s][v], 16, 64));
                mxa[s][v] = fmaxf(mxa[s][v], __shfl_xor(mxa[s][v], 32, 64));
            }
            s1a[s] += __shfl_xor(s1a[s], 16, 64); s1a[s] += __shfl_xor(s1a[s], 32, 64);
            s2a[s] += __shfl_xor(s2a[s], 16, 64); s2a[s] += __shfl_xor(s2a[s], 32, 64);
        }
        if (lq == 0) {
            int slot = blockIdx.x & (NSLOT - 1);
#pragma unroll
            for (int s = 0; s < 2; ++s) {
                int u = u0 + s * 16 + lr;
                float bdu = bd[u];
                float sg = (gd[u] < 0.f) ? -1.f : 1.f;
#pragma unroll
                for (int v = 0; v < 2; ++v)
                    outbuf[(size_t)u * KVOX + (k0 + v)] = fmaf(sg, mxa[s][v], bdu);
                atomicAdd(&slot3[slot * 256 + u], s1a[s]);
                atomicAdd(&slot3[slot * 256 + 128 + u], s2a[s]);
            }
        }
    }
}

__global__ __launch_bounds__(256) void k_final_inplace(const float* __restrict__ ws,
                                                       float* __restrict__ out) {
    int v = blockIdx.x * 256 + threadIdx.x;
    int u = blockIdx.y;
    if (v >= KVOX) return;
    float a = ws[PAR_A3 + u], c = ws[PAR_C3 + u];
    size_t idx = (size_t)u * KVOX + v;
    float y = a * out[idx] + c;
    out[idx] = (y >= 0.f) ? y : 0.1f * y;
}

// ---------------------------------------------------------------------------
extern "C" void kernel_launch(void* const* d_in, const int* in_sizes, int n_in,
                              void* d_out, int out_size, void* d_ws, size_t ws_size,
                              hipStream_t stream) {
    const float* x   = (const float*)d_in[0];
    const void*  coord = d_in[1];
    const float* W1  = (const float*)d_in[3];
    const float* b1  = (const float*)d_in[4];
    const float* g1  = (const float*)d_in[5];
    const float* be1 = (const float*)d_in[6];
    const float* W2  = (const float*)d_in[7];
    const float* b2  = (const float*)d_in[8];
    const float* g2  = (const float*)d_in[9];
    const float* be2 = (const float*)d_in[10];
    const float* Wd  = (const float*)d_in[11];
    const float* bd  = (const float*)d_in[12];
    const float* gd  = (const float*)d_in[13];
    const float* bed = (const float*)d_in[14];
    float* ws = (float*)d_ws;
    float* out = (float*)d_out;
    ushort* w2t = (ushort*)(ws + W2T_OFF);
    ushort* wdt = (ushort*)(ws + WDT_OFF);
    ushort* m3  = (ushort*)(ws + M3_OFF);
    uint* recs  = (uint*)(ws + H1G_OFF);

    size_t wsf = ws_size / 4;
    bool full = wsf >= (size_t)FULL_FLOATS;
    bool small = wsf >= (size_t)SMALL_FLOATS;

    hipMemsetAsync(d_ws, 0, (size_t)STATS_FLOATS * 4, stream);
    k_prep_stats1<<<64 + 256, 256, 0, stream>>>(x, W2, Wd, gd, w2t, wdt, ws + SLOTG_OFF);

    if (full) {
        k_stats2<true><<<KVOX / 4, 512, 0, stream>>>(x, W1, b1, g1, be1, w2t,
                                                     ws + SLOTG_OFF, ws + SLOT2_OFF, recs);
        k_stage3_reuse<<<KVOX / 4, 512, 0, stream>>>(recs, b2, g2, be2, w2t, wdt, bd, gd,
                                                     ws + SLOT2_OFF, ws + SLOT3_OFF, m3);
        k_final_ws<<<dim3((KVOX + 31) / 32, 4), 256, 0, stream>>>(m3, ws + SLOT3_OFF,
                                                                  gd, bed, bd, out);
    } else {
        k_affine1g<<<1, 64, 0, stream>>>(ws + SLOTG_OFF, W1, b1, g1, be1,
                                         ws + PAR_A1, ws + PAR_C1);
        k_stats2_fb<<<KVOX / 2, 256, 0, stream>>>(x, W1, b1, w2t, ws, ws + SLOT2_OFF);
        k_affine_b<<<1, 64, 0, stream>>>(ws + SLOT2_OFF, g2, be2, b2,
                                         ws + PAR_A2, ws + PAR_C2, 64);
        k_stage3_fb<<<KVOX / 2, 256, 0, stream>>>(x, W1, b1, b2, w2t, wdt, bd, gd, ws,
                                                  ws + SLOT3_OFF, out);
        k_affine_b3<<<1, 128, 0, stream>>>(ws + SLOT3_OFF, gd, bed, bd,
                                           ws + PAR_A3, ws + PAR_C3, 128);
        k_final_inplace<<<dim3((KVOX + 255) / 256, 128), 256, 0, stream>>>(ws, out);
        (void)small;
    }
    hipMemcpyAsync((char*)d_out + (size_t)128 * KVOX * 4, coord,
                   (size_t)KVOX * 4 * sizeof(int), hipMemcpyDeviceToDevice, stream);
}

// Round 10
// 146.634 us; speedup vs baseline: 1.2176x; 1.2176x over previous
//
#include <hip/hip_runtime.h>

#define KVOX 30000
#define TP 35
#define NPTS (KVOX * TP)
#define EPS_BN 1e-5f

typedef __attribute__((ext_vector_type(8))) short short8_t;   // 8 x bf16
typedef __attribute__((ext_vector_type(4))) float f32x4;

#define MFMA_BF16 __builtin_amdgcn_mfma_f32_16x16x32_bf16

// ---- ws layout (float offsets) ----
#define SLOTG_OFF 0                  // 64 x 40 (35 used: G[28] | Sx[7])
#define SLOT2_OFF 2560               // 64 x 128
#define SLOT3_OFF 10752              // 64 x 256
#define PAR_A1 27136
#define PAR_C1 27152
#define PAR_A2 27168
#define PAR_C2 27232
#define PAR_A3 27296
#define PAR_C3 27424
#define STATS_FLOATS 27136           // memset region: slots only
#define W2T_OFF 27552                // [64 u][32 k] bf16
#define WDT_OFF 28576                // [128 u][128 k] bf16 (sign-folded)
#define M3_OFF 36768                 // KVOX*128 bf16 = KVOX*64 floats
#define SMALL_FLOATS (36768 + KVOX * 64)
#define H1G_OFF SMALL_FLOATS         // per-4vox-block records
#define REC_DW 1224                  // 1120 h1(140rowsx16bf16) + 32 agg1 + 70 mask + 2 pad
#define FULL_FLOATS (H1G_OFF + (KVOX / 4) * REC_DW)

__device__ __forceinline__ ushort f2bf(float f) {
    uint r;
    asm("v_cvt_pk_bf16_f32 %0, %1, %2" : "=v"(r) : "v"(f), "v"(f));
    return (ushort)r;
}
__device__ __forceinline__ uint f2bf2(float lo, float hi) {
    uint r;
    asm("v_cvt_pk_bf16_f32 %0, %1, %2" : "=v"(r) : "v"(lo), "v"(hi));
    return r;
}
__device__ __forceinline__ float bf2f(ushort h) {
    union { uint u; float f; } v; v.u = ((uint)h) << 16; return v.f;
}

// ---------------------------------------------------------------------------
// prep (blocks 0..63): W2T; WDT with sign(gd) folded. stats1 (64+): Gram sums
// via f32x4 loads (4 points / 7 vec-loads per iteration).
// ---------------------------------------------------------------------------
__global__ __launch_bounds__(256) void k_prep_stats1(
    const float* __restrict__ x,
    const float* __restrict__ W2, const float* __restrict__ Wd,
    const float* __restrict__ gd,
    ushort* __restrict__ w2t, ushort* __restrict__ wdt,
    float* __restrict__ slotG) {
    if (blockIdx.x < 64) {
        int t = blockIdx.x * 256 + threadIdx.x;     // 0..16383
        if (t < 2048) {
            int u = t >> 5, k = t & 31;
            w2t[t] = f2bf(W2[k * 64 + u]);
        }
        int u = t >> 7, k = t & 127;
        float sg = (gd[u] < 0.f) ? -1.f : 1.f;
        wdt[t] = f2bf(Wd[k * 128 + u] * sg);
        return;
    }
    int bid = blockIdx.x - 64;                      // 0..255
    int tid = threadIdx.x;
    int gid = bid * 256 + tid;
    float sx[7], G[28];
#pragma unroll
    for (int c = 0; c < 7; ++c) sx[c] = 0.f;
#pragma unroll
    for (int i = 0; i < 28; ++i) G[i] = 0.f;
    for (size_t p4 = (size_t)gid * 4; p4 < NPTS; p4 += (size_t)65536 * 4) {
        const f32x4* xp = (const f32x4*)(x + p4 * 7);
        f32x4 q[7];
#pragma unroll
        for (int c = 0; c < 7; ++c) q[c] = xp[c];
#pragma unroll
        for (int j = 0; j < 4; ++j) {
            float xv[7];
#pragma unroll
            for (int c = 0; c < 7; ++c) {
                int idx = j * 7 + c;
                xv[c] = q[idx >> 2][idx & 3];
                sx[c] += xv[c];
            }
            int idx = 0;
#pragma unroll
            for (int i = 0; i < 7; ++i)
#pragma unroll
                for (int jj = i; jj < 7; ++jj) { G[idx] = fmaf(xv[i], xv[jj], G[idx]); ++idx; }
        }
    }
    int lane = tid & 63;
    int wv = tid >> 6;
    int slot = (bid * 4 + wv) & 63;
#pragma unroll
    for (int k = 0; k < 35; ++k) {
        float v = (k < 28) ? G[k] : sx[k - 28];
#pragma unroll
        for (int m = 32; m > 0; m >>= 1) v += __shfl_xor(v, m, 64);
        if (lane == 0) atomicAdd(&slotG[slot * 40 + k], v);
    }
}

// BN1 finalize from Gram stats
__global__ void k_affine1g(const float* __restrict__ slotG,
                           const float* __restrict__ W1, const float* __restrict__ b1,
                           const float* __restrict__ g1, const float* __restrict__ be1,
                           float* __restrict__ pa, float* __restrict__ pc, float invN) {
    __shared__ float red[35];
    int t = threadIdx.x;     // 64 threads
    if (t < 35) {
        float s = 0.f;
#pragma unroll
        for (int sl = 0; sl < 64; ++sl) s += slotG[sl * 40 + t];
        red[t] = s;
    }
    __syncthreads();
    if (t < 16) {
        float wv[7];
#pragma unroll
        for (int c = 0; c < 7; ++c) wv[c] = W1[c * 16 + t];
        float b = b1[t];
        float sw = 0.f;
#pragma unroll
        for (int c = 0; c < 7; ++c) sw = fmaf(red[28 + c], wv[c], sw);
        float gq = 0.f;
        int idx = 0;
#pragma unroll
        for (int i = 0; i < 7; ++i)
#pragma unroll
            for (int j = i; j < 7; ++j) {
                float coef = wv[i] * wv[j];
                if (i != j) coef *= 2.f;
                gq = fmaf(coef, red[idx], gq);
                ++idx;
            }
        float mr = sw * invN;
        float mean = mr + b;
        float ex2 = gq * invN + 2.f * b * mr + b * b;
        float var = ex2 - mean * mean;
        float av = g1[t] * rsqrtf(var + EPS_BN);
        pa[t] = av;
        pc[t] = be1[t] - mean * av;
    }
}

// Bias-folded BN finalize: slots hold sums of (pw - b)
__global__ void k_affine_b(const float* __restrict__ slots,
                           const float* __restrict__ g,
                           const float* __restrict__ be,
                           const float* __restrict__ bias,
                           float* __restrict__ pa, float* __restrict__ pc,
                           int C, float invN) {
    int u = threadIdx.x;
    if (u >= C) return;
    float s = 0.f, q = 0.f;
    for (int sl = 0; sl < 64; ++sl) {
        s += slots[sl * 2 * C + u];
        q += slots[sl * 2 * C + C + u];
    }
    float b = bias[u];
    float mr = s * invN;
    float mean = mr + b;
    float ex2 = q * invN + 2.f * b * mr + b * b;
    float var = ex2 - mean * mean;
    float av = g[u] * rsqrtf(var + EPS_BN);
    pa[u] = av;
    pc[u] = be[u] - mean * av;
}

// Sign-aware variant for BN3: slots hold sums of sgn(g)*(pw - b)
__global__ void k_affine_b3(const float* __restrict__ slots,
                            const float* __restrict__ g,
                            const float* __restrict__ be,
                            const float* __restrict__ bias,
                            float* __restrict__ pa, float* __restrict__ pc,
                            int C, float invN) {
    int u = threadIdx.x;
    if (u >= C) return;
    float s = 0.f, q = 0.f;
    for (int sl = 0; sl < 64; ++sl) {
        s += slots[sl * 2 * C + u];
        q += slots[sl * 2 * C + C + u];
    }
    float sg = (g[u] < 0.f) ? -1.f : 1.f;
    s *= sg;
    float b = bias[u];
    float mr = s * invN;
    float mean = mr + b;
    float ex2 = q * invN + 2.f * b * mr + b * b;
    float var = ex2 - mean * mean;
    float av = g[u] * rsqrtf(var + EPS_BN);
    pa[u] = av;
    pc[u] = be[u] - mean * av;
}

// ---------------------------------------------------------------------------
// Phase A, 4 voxels, 512 threads, x pre-staged in LDS (xl[980] floats).
// Rows = 4t+v (140 real + 4 pad = 144). h1 bf16 [144][24] masked (cols 0..15).
// agg1bf [4][16] bf16. lmask[144] f32. Bit-identical math to global-read form.
// ---------------------------------------------------------------------------
__device__ __forceinline__ void phaseA4(
    int tid,
    const float* __restrict__ xl,
    const float* __restrict__ W1, const float* __restrict__ b1,
    const float* __restrict__ a1, const float* __restrict__ c1,
    ushort* __restrict__ h1, float* __restrict__ lmask,
    float* __restrict__ aggp /*[7*64]*/, ushort* __restrict__ agg1bf /*[64]*/) {
    int u = tid & 15;
    int g = tid >> 4;      // 0..31
    int v = g & 3;
    int th = g >> 2;       // 0..7
    float pmax = 0.f;
    if (th < 7) {
        float b1u = b1[u];
        float a1u = a1[u], c1u = c1[u];
        float w1c[7];
#pragma unroll
        for (int c = 0; c < 7; ++c) w1c[c] = W1[c * 16 + u];
#pragma unroll
        for (int i = 0; i < 5; ++i) {
            int t = th * 5 + i;
            const float* xp = xl + v * 245 + t * 7;
            float xv[7];
            float sum7 = 0.f;
#pragma unroll
            for (int c = 0; c < 7; ++c) { xv[c] = xp[c]; sum7 += xv[c]; }
            float mkv = (sum7 != 0.f) ? 1.f : 0.f;
            int row = 4 * t + v;
            if (u == 0) lmask[row] = mkv;
            float val = b1u;
#pragma unroll
            for (int c = 0; c < 7; ++c) val = fmaf(xv[c], w1c[c], val);
            val = fmaxf(fmaf(a1u, val, c1u), 0.f);
            pmax = fmaxf(pmax, val);                 // unmasked (ref semantics)
            h1[row * 24 + u] = f2bf(val * mkv);
        }
    } else {
        // wave 7: zero pad rows 140..143
        int row = 140 + v;
        h1[row * 24 + u] = 0;
        if (u == 0) lmask[row] = 0.f;
    }
    int w = tid >> 6;
    int lane = tid & 63;                              // lane = v*16+u
    if (w < 7) aggp[w * 64 + lane] = pmax;
    __syncthreads();
    if (tid < 64) {
        float m = aggp[tid];
#pragma unroll
        for (int ww = 1; ww < 7; ++ww) m = fmaxf(m, aggp[ww * 64 + tid]);
        agg1bf[tid] = f2bf(m);                        // layout [v*16+u]
    }
    __syncthreads();
}

// ---------------------------------------------------------------------------
// S2: BN2 stats via rank-1 MFMA (4 voxels, 512 thr); dumps record if DUMP.
// x staged to LDS once (245 coalesced f32x4 loads) — kills 35 scalar
// global loads/thread (16x redundant across the u-group).
// ---------------------------------------------------------------------------
template <bool DUMP>
__global__ __launch_bounds__(512, 8) void k_stats2(
    const float* __restrict__ x,
    const float* __restrict__ W1, const float* __restrict__ b1,
    const ushort* __restrict__ w2t,
    const float* __restrict__ ws,
    float* __restrict__ slot2, uint* __restrict__ recs) {
    __shared__ __align__(16) ushort h1[144 * 24];
    __shared__ __align__(16) float xlds[980];
    __shared__ float lmask[144];
    __shared__ float aggp[7 * 64];
    __shared__ __align__(16) ushort agg1bf[64];
    __shared__ __align__(16) uint zeros16[4];
    int tid = threadIdx.x;
    int k0 = blockIdx.x * 4;
    if (tid < 4) zeros16[tid] = 0;
    // ---- stage x slice: 4 voxels x 245 floats, 16B-aligned, coalesced ----
    {
        const f32x4* xg = (const f32x4*)(x + (size_t)k0 * 245);
        if (tid < 245) ((f32x4*)xlds)[tid] = xg[tid];
    }
    __syncthreads();
    phaseA4(tid, xlds, W1, b1, ws + PAR_A1, ws + PAR_C1, h1, lmask, aggp, agg1bf);
    if (DUMP) {
        uint* rec = recs + (size_t)blockIdx.x * REC_DW;
        const uint* h1dw = (const uint*)h1;
        for (int i = tid; i < 1120; i += 512) rec[i] = h1dw[(i >> 3) * 12 + (i & 7)];
        if (tid < 32) rec[1120 + tid] = ((const uint*)agg1bf)[tid];
        if (tid < 70) rec[1152 + tid] = f2bf2(lmask[2 * tid], lmask[2 * tid + 1]);
    }
    int w = tid >> 6, lane = tid & 63, lq = lane >> 4, lr = lane & 15;
    int mh = w >> 2, uq = w & 3;
    int u = uq * 16 + lr;
    short8_t bB = *(const short8_t*)(w2t + u * 32 + (lq & 1) * 8);
    short8_t bP = *(const short8_t*)(w2t + u * 32 + 16 + (lq & 1) * 8);
    const ushort* pap = (lq < 2) ? (agg1bf + (lr & 3) * 16 + (lq & 1) * 8) : (const ushort*)zeros16;
    short8_t pAf = *(const short8_t*)pap;
    f32x4 aP = {0.f, 0.f, 0.f, 0.f};
    aP = MFMA_BF16(pAf, bP, aP, 0, 0, 0);
    f32x4 p1;
    p1[0] = __shfl(aP[0], lr, 64); p1[1] = __shfl(aP[1], lr, 64);
    p1[2] = __shfl(aP[2], lr, 64); p1[3] = __shfl(aP[3], lr, 64);
    f32x4 s1p = {0.f, 0.f, 0.f, 0.f}, s2p = {0.f, 0.f, 0.f, 0.f};
    int mt0 = mh ? 5 : 0, mt1 = mh ? 9 : 5;
    for (int mt = mt0; mt < mt1; ++mt) {
        const ushort* ha = (lq < 2) ? (h1 + (mt * 16 + lr) * 24 + (lq & 1) * 8) : (const ushort*)zeros16;
        short8_t af = *(const short8_t*)ha;
        f32x4 acc = {0.f, 0.f, 0.f, 0.f};
        acc = MFMA_BF16(af, bB, acc, 0, 0, 0);
        f32x4 mk = *(const f32x4*)(lmask + mt * 16 + lq * 4);
        f32x4 am = (acc + p1) * mk;
        s1p += am;
        s2p += am * am;
    }
    float s1 = s1p[0] + s1p[1] + s1p[2] + s1p[3];
    float s2 = s2p[0] + s2p[1] + s2p[2] + s2p[3];
    s1 += __shfl_xor(s1, 16, 64); s1 += __shfl_xor(s1, 32, 64);
    s2 += __shfl_xor(s2, 16, 64); s2 += __shfl_xor(s2, 32, 64);
    if (lq == 0) {
        int slot = blockIdx.x & 63;
        atomicAdd(&slot2[slot * 128 + u], s1);
        atomicAdd(&slot2[slot * 128 + 64 + u], s2);
    }
}

// ---------------------------------------------------------------------------
// S3 REUSE: 4 voxels, 512 thr. Stage record -> phase B (atomicMax agg2 via
// uint bits, kills pack barrier) -> phase C. Only 2 barriers per block.
// ---------------------------------------------------------------------------
__global__ __launch_bounds__(512, 8) void k_stage3_reuse(
    const uint* __restrict__ recs,
    const float* __restrict__ b2,
    const ushort* __restrict__ w2t, const ushort* __restrict__ wdt,
    const float* __restrict__ bd, const float* __restrict__ gd,
    const float* __restrict__ ws,
    float* __restrict__ slot3, ushort* __restrict__ m3) {
    __shared__ __align__(16) ushort h1[144 * 24];
    __shared__ __align__(16) ushort h2[144 * 72];
    __shared__ float lmask[144];
    __shared__ __align__(16) uint aggfU[4 * 68];     // [vox][68] f32-bits (max)
    __shared__ __align__(16) ushort agg1bf[64];
    __shared__ __align__(16) uint zeros16[4];
    int tid = threadIdx.x;
    int k0 = blockIdx.x * 4;
    int w = tid >> 6, lane = tid & 63, lq = lane >> 4, lr = lane & 15;

    // ---- staging ----
    {
        const uint* rec = recs + (size_t)blockIdx.x * REC_DW;
        uint* h1dw = (uint*)h1;
        {
            int i = tid;              h1dw[(i >> 3) * 12 + (i & 7)] = rec[i];
            i = tid + 512;            h1dw[(i >> 3) * 12 + (i & 7)] = rec[i];
            i = tid + 1024; if (i < 1120) h1dw[(i >> 3) * 12 + (i & 7)] = rec[i];
        }
        if (tid < 48) h1dw[140 * 12 + tid] = 0u;     // pad rows 140..143
        if (tid < 32) ((uint*)agg1bf)[tid] = rec[1120 + tid];
        if (tid < 72) {
            if (tid < 70) {
                uint mw = rec[1152 + tid];
                lmask[2 * tid] = bf2f((ushort)(mw & 0xffffu));
                lmask[2 * tid + 1] = bf2f((ushort)(mw >> 16));
            } else {
                int j = 140 + (tid - 70) * 2;
                lmask[j] = 0.f; lmask[j + 1] = 0.f;
            }
        }
        if (tid < 272) aggfU[tid] = 0u;
        if (tid < 4) zeros16[tid] = 0u;
    }
    __syncthreads();

    // ---- phase B: waves (mh = rows half, uq = u quarter); vox = acc slot r ----
    {
        int mh = w >> 2, uq = w & 3;
        int u = uq * 16 + lr;
        short8_t bB = *(const short8_t*)(w2t + u * 32 + (lq & 1) * 8);
        short8_t bP = *(const short8_t*)(w2t + u * 32 + 16 + (lq & 1) * 8);
        const ushort* pap = (lq < 2) ? (agg1bf + (lr & 3) * 16 + (lq & 1) * 8) : (const ushort*)zeros16;
        short8_t pAf = *(const short8_t*)pap;
        f32x4 aP = {0.f, 0.f, 0.f, 0.f};
        aP = MFMA_BF16(pAf, bP, aP, 0, 0, 0);
        f32x4 p1;
        p1[0] = __shfl(aP[0], lr, 64); p1[1] = __shfl(aP[1], lr, 64);
        p1[2] = __shfl(aP[2], lr, 64); p1[3] = __shfl(aP[3], lr, 64);
        float a2u = ws[PAR_A2 + u];
        float c2u = fmaf(a2u, b2[u], ws[PAR_C2 + u]);
        f32x4 av = {0.f, 0.f, 0.f, 0.f};
        int mt0 = mh ? 5 : 0, mt1 = mh ? 9 : 5;
        for (int mt = mt0; mt < mt1; ++mt) {
            const ushort* ha = (lq < 2) ? (h1 + (mt * 16 + lr) * 24 + (lq & 1) * 8) : (const ushort*)zeros16;
            short8_t af = *(const short8_t*)ha;
            f32x4 acc = {0.f, 0.f, 0.f, 0.f};
            acc = MFMA_BF16(af, bB, acc, 0, 0, 0);
            f32x4 mk = *(const f32x4*)(lmask + mt * 16 + lq * 4);
            int m0 = mt * 16 + lq * 4;
            f32x4 vals;
#pragma unroll
            for (int r = 0; r < 4; ++r) {
                float am = (acc[r] + p1[r]) * mk[r];
                float val = fmaxf(fmaf(a2u, am, c2u), 0.f);
                h2[(m0 + r) * 72 + u] = f2bf(val);
                vals[r] = val;
            }
            if (!(mt == 8 && lq == 3)) {             // exclude pad rows 140..143
#pragma unroll
                for (int r = 0; r < 4; ++r) av[r] = fmaxf(av[r], vals[r]);
            }
        }
#pragma unroll
        for (int r = 0; r < 4; ++r) {
            av[r] = fmaxf(av[r], __shfl_xor(av[r], 16, 64));
            av[r] = fmaxf(av[r], __shfl_xor(av[r], 32, 64));
        }
        if (lq == 0) {
#pragma unroll
            for (int r = 0; r < 4; ++r)
                atomicMax(&aggfU[r * 68 + u], __float_as_uint(av[r]));
        }
    }
    __syncthreads();

    // ---- phase C: pw3 = h2@Wd[0:64] + mask*proj2(agg2) ----
    {
        int u = w * 16 + lr;
        short8_t bM0 = *(const short8_t*)(wdt + u * 128 + lq * 8);
        short8_t bM1 = *(const short8_t*)(wdt + u * 128 + 32 + lq * 8);
        short8_t bP0 = *(const short8_t*)(wdt + u * 128 + 64 + lq * 8);
        short8_t bP1 = *(const short8_t*)(wdt + u * 128 + 96 + lq * 8);
        const float* aggf = (const float*)aggfU;
        f32x4 q0 = *(const f32x4*)(aggf + (lr & 3) * 68 + lq * 8);
        f32x4 q1 = *(const f32x4*)(aggf + (lr & 3) * 68 + lq * 8 + 4);
        f32x4 q2 = *(const f32x4*)(aggf + (lr & 3) * 68 + 32 + lq * 8);
        f32x4 q3 = *(const f32x4*)(aggf + (lr & 3) * 68 + 32 + lq * 8 + 4);
        union { uint uu[4]; short8_t s8; } pc0, pc1;
        pc0.uu[0] = f2bf2(q0[0], q0[1]); pc0.uu[1] = f2bf2(q0[2], q0[3]);
        pc0.uu[2] = f2bf2(q1[0], q1[1]); pc0.uu[3] = f2bf2(q1[2], q1[3]);
        pc1.uu[0] = f2bf2(q2[0], q2[1]); pc1.uu[1] = f2bf2(q2[2], q2[3]);
        pc1.uu[2] = f2bf2(q3[0], q3[1]); pc1.uu[3] = f2bf2(q3[2], q3[3]);
        f32x4 aP = {0.f, 0.f, 0.f, 0.f};
        aP = MFMA_BF16(pc0.s8, bP0, aP, 0, 0, 0);
        aP = MFMA_BF16(pc1.s8, bP1, aP, 0, 0, 0);
        f32x4 p2;
        p2[0] = __shfl(aP[0], lr, 64); p2[1] = __shfl(aP[1], lr, 64);
        p2[2] = __shfl(aP[2], lr, 64); p2[3] = __shfl(aP[3], lr, 64);
        f32x4 s1p = {0.f, 0.f, 0.f, 0.f}, s2p = {0.f, 0.f, 0.f, 0.f};
        f32x4 mx = {-1e30f, -1e30f, -1e30f, -1e30f};
#pragma unroll
        for (int mt = 0; mt < 9; ++mt) {
            const ushort* hrow = h2 + (mt * 16 + lr) * 72;
            short8_t a0 = *(const short8_t*)(hrow + lq * 8);
            short8_t a1 = *(const short8_t*)(hrow + 32 + lq * 8);
            f32x4 acc = {0.f, 0.f, 0.f, 0.f};
            acc = MFMA_BF16(a0, bM0, acc, 0, 0, 0);
            acc = MFMA_BF16(a1, bM1, acc, 0, 0, 0);
            f32x4 mk = *(const f32x4*)(lmask + mt * 16 + lq * 4);
            f32x4 am = (acc + p2) * mk;
            s1p += am;
            s2p += am * am;
            if (mt < 8) {
#pragma unroll
                for (int r = 0; r < 4; ++r) mx[r] = fmaxf(mx[r], am[r]);
            } else if (lq < 3) {                     // rows 128..139 only
#pragma unroll
                for (int r = 0; r < 4; ++r) mx[r] = fmaxf(mx[r], am[r]);
            }
        }
#pragma unroll
        for (int r = 0; r < 4; ++r) {
            mx[r] = fmaxf(mx[r], __shfl_xor(mx[r], 16, 64));
            mx[r] = fmaxf(mx[r], __shfl_xor(mx[r], 32, 64));
        }
        float s1 = s1p[0] + s1p[1] + s1p[2] + s1p[3];
        float s2 = s2p[0] + s2p[1] + s2p[2] + s2p[3];
        s1 += __shfl_xor(s1, 16, 64); s1 += __shfl_xor(s1, 32, 64);
        s2 += __shfl_xor(s2, 16, 64); s2 += __shfl_xor(s2, 32, 64);
        if (lq == 0) {
            float sg = (gd[u] < 0.f) ? -1.f : 1.f;
            float bdu = bd[u];
#pragma unroll
            for (int r = 0; r < 4; ++r)
                m3[(size_t)(k0 + r) * 128 + u] = f2bf(fmaf(sg, mx[r], bdu));
            int slot = blockIdx.x & 63;
            atomicAdd(&slot3[slot * 256 + u], s1);
            atomicAdd(&slot3[slot * 256 + 128 + u], s2);
        }
    }
}

// ---------------------------------------------------------------------------
// Legacy 2-vox phase A + full-recompute fallback (small / tiny ws tiers)
// ---------------------------------------------------------------------------
__device__ __forceinline__ void phaseA_leg(
    int k0, int tid,
    const float* __restrict__ x,
    const float* __restrict__ W1, const float* __restrict__ b1,
    const float* __restrict__ a1, const float* __restrict__ c1,
    ushort* __restrict__ h1, float* __restrict__ lmask, float* __restrict__ aggp) {
    int u = tid & 15;
    int g = tid >> 4;
    int v = g & 1;
    int th = g >> 1;
    float pmax = 0.f;
    if (th < 7) {
        float b1u = b1[u];
        float a1u = a1[u], c1u = c1[u];
        float w1c[7];
#pragma unroll
        for (int c = 0; c < 7; ++c) w1c[c] = W1[c * 16 + u];
#pragma unroll
        for (int i = 0; i < 5; ++i) {
            int t = th * 5 + i;
            const float* xp = x + ((size_t)(k0 + v) * TP + t) * 7;
            float xv[7];
            float sum7 = 0.f;
#pragma unroll
            for (int c = 0; c < 7; ++c) { xv[c] = xp[c]; sum7 += xv[c]; }
            float mkv = (sum7 != 0.f) ? 1.f : 0.f;
            if (u == 0) lmask[v * TP + t] = mkv;
            float val = b1u;
#pragma unroll
            for (int c = 0; c < 7; ++c) val = fmaf(xv[c], w1c[c], val);
            val = fmaxf(fmaf(a1u, val, c1u), 0.f);
            pmax = fmaxf(pmax, val);
            h1[(v * TP + t) * 40 + u] = f2bf(val * mkv);
        }
    } else {
#pragma unroll
        for (int i = 0; i < 5; ++i) {
            int row = 70 + (g & 1) * 5 + i;
            h1[row * 40 + u] = 0;
            if (u == 0) lmask[row] = 0.f;
        }
    }
    pmax = fmaxf(pmax, __shfl_xor(pmax, 32, 64));
    int w = tid >> 6;
    int lane = tid & 63;
    if (lane < 32) aggp[w * 32 + lane] = pmax;
    __syncthreads();
    {
        int uu = tid & 15;
        int r0 = tid >> 4;
        float g0 = fmaxf(fmaxf(aggp[uu], aggp[32 + uu]),
                         fmaxf(aggp[64 + uu], aggp[96 + uu]));
        float g1v = fmaxf(fmaxf(aggp[16 + uu], aggp[48 + uu]),
                          fmaxf(aggp[80 + uu], aggp[112 + uu]));
        ushort a0 = f2bf(g0), a1b = f2bf(g1v);
#pragma unroll
        for (int j = 0; j < 5; ++j) {
            int row = r0 + j * 16;
            float mkv = lmask[row];
            h1[row * 40 + 16 + uu] = (mkv != 0.f) ? ((row < TP) ? a0 : a1b) : (ushort)0;
        }
    }
    __syncthreads();
}

template <bool WSPATH>
__global__ __launch_bounds__(256) void k_stage3_full(
    const float* __restrict__ x,
    const float* __restrict__ W1, const float* __restrict__ b1,
    const float* __restrict__ b2,
    const ushort* __restrict__ w2t, const ushort* __restrict__ wdt,
    const float* __restrict__ bd, const float* __restrict__ gd,
    const float* __restrict__ ws,
    float* __restrict__ slot3,
    ushort* __restrict__ m3, float* __restrict__ outbuf) {
    __shared__ __align__(16) ushort h1[80 * 40];
    __shared__ __align__(16) ushort h2[80 * 136];
    __shared__ float lmask[80];
    __shared__ float aggp[128];
    __shared__ ushort agg2bf[128];
    int tid = threadIdx.x;
    int k0 = blockIdx.x * 2;
    int w = tid >> 6, lane = tid & 63, lq = lane >> 4, lr = lane & 15;
    phaseA_leg(k0, tid, x, W1, b1, ws + PAR_A1, ws + PAR_C1, h1, lmask, aggp);

    int u0 = w * 32;
    short8_t bfr[2][4];
#pragma unroll
    for (int s = 0; s < 2; ++s)
#pragma unroll
        for (int kk = 0; kk < 4; ++kk)
            bfr[s][kk] = *(const short8_t*)(wdt + ((u0 + s * 16 + lr) * 128 + kk * 32 + lq * 8));

    {
        int u = w * 16 + lr;
        short8_t bfrag = *(const short8_t*)(w2t + u * 32 + lq * 8);
        float a2u = ws[PAR_A2 + u];
        float c2p = fmaf(a2u, b2[u], ws[PAR_C2 + u]);
        float aggv0 = 0.f, aggv1 = 0.f;
#pragma unroll
        for (int mt = 0; mt < 5; ++mt) {
            short8_t afrag = *(const short8_t*)(h1 + (mt * 16 + lr) * 40 + lq * 8);
            f32x4 acc = {0.f, 0.f, 0.f, 0.f};
            acc = MFMA_BF16(afrag, bfrag, acc, 0, 0, 0);
#pragma unroll
            for (int r = 0; r < 4; ++r) {
                int m = mt * 16 + lq * 4 + r;
                float val = fmaxf(fmaf(a2u, acc[r], c2p), 0.f);
                float vm = (m < 70) ? val : 0.f;
                if (m < TP) aggv0 = fmaxf(aggv0, vm); else aggv1 = fmaxf(aggv1, vm);
                h2[m * 136 + u] = f2bf(val * lmask[m]);
            }
        }
        aggv0 = fmaxf(aggv0, __shfl_xor(aggv0, 16, 64));
        aggv0 = fmaxf(aggv0, __shfl_xor(aggv0, 32, 64));
        aggv1 = fmaxf(aggv1, __shfl_xor(aggv1, 16, 64));
        aggv1 = fmaxf(aggv1, __shfl_xor(aggv1, 32, 64));
        if (lq == 0) { agg2bf[u] = f2bf(aggv0); agg2bf[64 + u] = f2bf(aggv1); }
    }
    __syncthreads();
    {
        int c = tid & 63;
        int r0 = tid >> 6;
        ushort a0 = agg2bf[c], a1v = agg2bf[64 + c];
#pragma unroll
        for (int j = 0; j < 20; ++j) {
            int row = r0 + j * 4;
            float mkv = lmask[row];
            h2[row * 136 + 64 + c] = (mkv != 0.f) ? ((row < TP) ? a0 : a1v) : (ushort)0;
        }
    }
    __syncthreads();
    {
        float mxa[2][2], s1a[2], s2a[2];
#pragma unroll
        for (int s = 0; s < 2; ++s) {
            s1a[s] = 0.f; s2a[s] = 0.f;
            mxa[s][0] = -1e30f; mxa[s][1] = -1e30f;
        }
#pragma unroll
        for (int mt = 0; mt < 5; ++mt) {
            short8_t af[4];
#pragma unroll
            for (int kk = 0; kk < 4; ++kk)
                af[kk] = *(const short8_t*)(h2 + (mt * 16 + lr) * 136 + kk * 32 + lq * 8);
#pragma unroll
            for (int s = 0; s < 2; ++s) {
                f32x4 acc = {0.f, 0.f, 0.f, 0.f};
#pragma unroll
                for (int kk = 0; kk < 4; ++kk)
                    acc = MFMA_BF16(af[kk], bfr[s][kk], acc, 0, 0, 0);
#pragma unroll
                for (int r = 0; r < 4; ++r) {
                    float a = acc[r];
                    s1a[s] += a;
                    s2a[s] = fmaf(a, a, s2a[s]);
                    int m = mt * 16 + lq * 4 + r;
                    if (mt <= 1) mxa[s][0] = fmaxf(mxa[s][0], a);
                    else if (mt == 3) mxa[s][1] = fmaxf(mxa[s][1], a);
                    else if (mt == 2) { if (m < TP) mxa[s][0] = fmaxf(mxa[s][0], a); else mxa[s][1] = fmaxf(mxa[s][1], a); }
                    else { if (m < 70) mxa[s][1] = fmaxf(mxa[s][1], a); }
                }
            }
        }
#pragma unroll
        for (int s = 0; s < 2; ++s) {
#pragma unroll
            for (int v = 0; v < 2; ++v) {
                mxa[s][v] = fmaxf(mxa[s][v], __shfl_xor(mxa[s][v], 16, 64));
                mxa[s][v] = fmaxf(mxa[s][v], __shfl_xor(mxa[s][v], 32, 64));
            }
            s1a[s] += __shfl_xor(s1a[s], 16, 64); s1a[s] += __shfl_xor(s1a[s], 32, 64);
            s2a[s] += __shfl_xor(s2a[s], 16, 64); s2a[s] += __shfl_xor(s2a[s], 32, 64);
        }
        if (lq == 0) {
            int slot = blockIdx.x & 63;
#pragma unroll
            for (int s = 0; s < 2; ++s) {
                int u = u0 + s * 16 + lr;
                float bdu = bd[u];
                float sg = (gd[u] < 0.f) ? -1.f : 1.f;
#pragma unroll
                for (int v = 0; v < 2; ++v) {
                    float res = fmaf(sg, mxa[s][v], bdu);
                    if (WSPATH) m3[(size_t)(k0 + v) * 128 + u] = f2bf(res);
                    else        outbuf[(size_t)u * KVOX + (k0 + v)] = res;
                }
                atomicAdd(&slot3[slot * 256 + u], s1a[s]);
                atomicAdd(&slot3[slot * 256 + 128 + u], s2a[s]);
            }
        }
    }
}

// ---------------------------------------------------------------------------
// Finalize: out[u][k] = leaky(bn3(m3[k][u])) via LDS transpose (m3 = bf16)
// ---------------------------------------------------------------------------
__global__ __launch_bounds__(256) void k_final_ws(const ushort* __restrict__ m3,
                                                  const float* __restrict__ ws,
                                                  float* __restrict__ out) {
    __shared__ float tile[32][33];
    int tx = threadIdx.x & 31;
    int ty = threadIdx.x >> 5;
    int v0 = blockIdx.x * 32;
    int u0 = blockIdx.y * 32;
    const float* a3 = ws + PAR_A3;
    const float* c3 = ws + PAR_C3;
#pragma unroll
    for (int r = ty; r < 32; r += 8) {
        int v = v0 + r, u = u0 + tx;
        float y = 0.f;
        if (v < KVOX) {
            float a = a3[u], c = c3[u];
            float val = bf2f(m3[(size_t)v * 128 + u]);
            y = a * val + c;
            y = (y >= 0.f) ? y : 0.1f * y;
        }
        tile[r][tx] = y;
    }
    __syncthreads();
#pragma unroll
    for (int r = ty; r < 32; r += 8) {
        int u = u0 + r, v = v0 + tx;
        if (v < KVOX) out[(size_t)u * KVOX + v] = tile[tx][r];
    }
}

__global__ __launch_bounds__(256) void k_final_inplace(const float* __restrict__ ws,
                                                       float* __restrict__ out) {
    int v = blockIdx.x * 256 + threadIdx.x;
    int u = blockIdx.y;
    if (v >= KVOX) return;
    float a = ws[PAR_A3 + u], c = ws[PAR_C3 + u];
    size_t idx = (size_t)u * KVOX + v;
    float y = a * out[idx] + c;
    out[idx] = (y >= 0.f) ? y : 0.1f * y;
}

// ---------------------------------------------------------------------------
extern "C" void kernel_launch(void* const* d_in, const int* in_sizes, int n_in,
                              void* d_out, int out_size, void* d_ws, size_t ws_size,
                              hipStream_t stream) {
    const float* x   = (const float*)d_in[0];
    const void*  coord = d_in[1];
    const float* W1  = (const float*)d_in[3];
    const float* b1  = (const float*)d_in[4];
    const float* g1  = (const float*)d_in[5];
    const float* be1 = (const float*)d_in[6];
    const float* W2  = (const float*)d_in[7];
    const float* b2  = (const float*)d_in[8];
    const float* g2  = (const float*)d_in[9];
    const float* be2 = (const float*)d_in[10];
    const float* Wd  = (const float*)d_in[11];
    const float* bd  = (const float*)d_in[12];
    const float* gd  = (const float*)d_in[13];
    const float* bed = (const float*)d_in[14];
    float* ws = (float*)d_ws;
    float* out = (float*)d_out;
    ushort* w2t = (ushort*)(ws + W2T_OFF);
    ushort* wdt = (ushort*)(ws + WDT_OFF);
    ushort* m3  = (ushort*)(ws + M3_OFF);
    uint* recs  = (uint*)(ws + H1G_OFF);

    size_t wsf = ws_size / 4;
    bool full = wsf >= (size_t)FULL_FLOATS;
    bool small = wsf >= (size_t)SMALL_FLOATS;
    const float invN = 1.f / (float)NPTS;

    hipMemsetAsync(d_ws, 0, (size_t)STATS_FLOATS * 4, stream);

    k_prep_stats1<<<64 + 256, 256, 0, stream>>>(x, W2, Wd, gd, w2t, wdt, ws + SLOTG_OFF);
    k_affine1g<<<1, 64, 0, stream>>>(ws + SLOTG_OFF, W1, b1, g1, be1, ws + PAR_A1, ws + PAR_C1, invN);
    if (full)
        k_stats2<true><<<KVOX / 4, 512, 0, stream>>>(x, W1, b1, w2t, ws, ws + SLOT2_OFF, recs);
    else
        k_stats2<false><<<KVOX / 4, 512, 0, stream>>>(x, W1, b1, w2t, ws, ws + SLOT2_OFF, recs);
    k_affine_b<<<1, 64, 0, stream>>>(ws + SLOT2_OFF, g2, be2, b2, ws + PAR_A2, ws + PAR_C2, 64, invN);

    if (full) {
        k_stage3_reuse<<<KVOX / 4, 512, 0, stream>>>(recs, b2, w2t, wdt, bd, gd, ws,
                                                     ws + SLOT3_OFF, m3);
        k_affine_b3<<<1, 128, 0, stream>>>(ws + SLOT3_OFF, gd, bed, bd, ws + PAR_A3, ws + PAR_C3, 128, invN);
        k_final_ws<<<dim3((KVOX + 31) / 32, 4), 256, 0, stream>>>(m3, ws, out);
    } else if (small) {
        k_stage3_full<true><<<KVOX / 2, 256, 0, stream>>>(x, W1, b1, b2, w2t, wdt, bd, gd, ws,
                                                          ws + SLOT3_OFF, m3, out);
        k_affine_b3<<<1, 128, 0, stream>>>(ws + SLOT3_OFF, gd, bed, bd, ws + PAR_A3, ws + PAR_C3, 128, invN);
        k_final_ws<<<dim3((KVOX + 31) / 32, 4), 256, 0, stream>>>(m3, ws, out);
    } else {
        k_stage3_full<false><<<KVOX / 2, 256, 0, stream>>>(x, W1, b1, b2, w2t, wdt, bd, gd, ws,
                                                           ws + SLOT3_OFF, m3, out);
        k_affine_b3<<<1, 128, 0, stream>>>(ws + SLOT3_OFF, gd, bed, bd, ws + PAR_A3, ws + PAR_C3, 128, invN);
        k_final_inplace<<<dim3((KVOX + 255) / 256, 128), 256, 0, stream>>>(ws, out);
    }
    hipMemcpyAsync((char*)d_out + (size_t)128 * KVOX * 4, coord,
                   (size_t)KVOX * 4 * sizeof(int), hipMemcpyDeviceToDevice, stream);
}